// Round 5
// baseline (402.303 us; speedup 1.0000x reference)
//
#include <hip/hip_runtime.h>
#include <hip/hip_bf16.h>
#include <math.h>

#define DM 768
#define NH 12
#define DH 64
#define DMLP 3072
#define BATCH 8
#define SEQ 1024
#define NTOK (BATCH*SEQ)
#define QKVN (3*DM)
#define LN_EPS 1e-5f
#define QSCALE 0.18033688011f   /* 0.125 * log2(e), folded into Q */

typedef __hip_bfloat16 bf16;
typedef __attribute__((ext_vector_type(8))) short bf16x8;
typedef __attribute__((ext_vector_type(4))) short s16x4;
typedef __attribute__((ext_vector_type(4))) float f32x4;

#define MFMA16(a,b,c) __builtin_amdgcn_mfma_f32_16x16x32_bf16((a),(b),(c),0,0,0)

__device__ __forceinline__ short f2bs(float f){
    bf16 h = __float2bfloat16(f); short s; __builtin_memcpy(&s, &h, 2); return s;
}

// gelu_new(x) = x * sigmoid(2c(x + 0.044715 x^3)), c = sqrt(2/pi). ~7 VALU ops.
__device__ __forceinline__ float gelu_f(float x){
    float y = 1.5957691216057308f*(x + 0.044715f*x*x*x);
    return x * __builtin_amdgcn_rcpf(1.0f + __expf(-y));
}

// Direct global->LDS async copy, 16B/lane. LDS dest is WAVE-UNIFORM base
// (HW writes lane i at base + i*16B); global source is per-lane (carries the
// swizzle). Tracked by vmcnt.
__device__ __forceinline__ void gld16(const void* g, void* l){
    __builtin_amdgcn_global_load_lds((__attribute__((address_space(1))) unsigned int*)g,
                                     (__attribute__((address_space(3))) unsigned int*)l,
                                     16, 0, 0);
}

// XCD-aware block decode: 1D grid, xcd = bid&7 (HW round-robin heuristic).
__device__ __forceinline__ void xcd_map(int NXB, int& bx, int& by){
    int bid = blockIdx.x;
    int xcd = bid & 7, slot = bid >> 3;
    int bands = (gridDim.x >> 3) / NXB;
    by = xcd * bands + slot / NXB;
    bx = slot % NXB;
}

// ---------------- unified weight prep: all transposes + bias concat, 1 launch ---------
__global__ __launch_bounds__(256) void prep_all(const float* __restrict__ Wq,
                                                const float* __restrict__ Wk,
                                                const float* __restrict__ Wv,
                                                const float* __restrict__ WO,
                                                const float* __restrict__ Wout,
                                                const float* __restrict__ bQ,
                                                const float* __restrict__ bK,
                                                const float* __restrict__ bV,
                                                short* __restrict__ wqkvT,
                                                short* __restrict__ WOT,
                                                short* __restrict__ WoutT,
                                                float* __restrict__ bias_qkv)
{
    int bid = blockIdx.x;
    if (bid == 4608){
        for (int idx = threadIdx.x; idx < QKVN; idx += 256){
            int which = idx / DM, hc = idx % DM;
            const float* b = (which == 0) ? bQ : ((which == 1) ? bK : bV);
            bias_qkv[idx] = b[hc];
        }
        return;
    }
    __shared__ float t[32][33];
    const float* in; short* o; int srcN, dstK, n0, k0;
    if (bid < 1728){
        int bx = bid & 1, rem = bid >> 1;
        int byy = rem % 24, bz = rem / 24;
        int which = bz / 12, h = bz % 12;
        in = (which == 0 ? Wq : which == 1 ? Wk : Wv) + (size_t)h*DM*DH;
        o  = wqkvT + ((size_t)which*DM + h*DH)*DM;
        srcN = DH; dstK = DM; n0 = bx*32; k0 = byy*32;
    } else if (bid < 2304){
        int idx = bid - 1728;
        in = WO; o = WOT; srcN = DM; dstK = DM;
        n0 = (idx % 24)*32; k0 = (idx / 24)*32;
    } else {
        int idx = bid - 2304;
        in = Wout; o = WoutT; srcN = DM; dstK = DMLP;
        n0 = (idx % 24)*32; k0 = (idx / 24)*32;
    }
    int tx = threadIdx.x & 31, ty = threadIdx.x >> 5;
    #pragma unroll
    for (int i = 0; i < 32; i += 8)
        t[ty+i][tx] = in[(size_t)(k0+ty+i)*srcN + n0+tx];
    __syncthreads();
    #pragma unroll
    for (int i = 0; i < 32; i += 8)
        o[(size_t)(n0+ty+i)*dstK + k0+tx] = f2bs(t[tx][ty+i]);
}

// ---------------- transpose + fp32->bf16 convert: out[N][K] = in[K][N] ----------------
__global__ __launch_bounds__(256) void transpose_cvt(const float* __restrict__ in,
                                                     short* __restrict__ out,
                                                     int K, int N)
{
    __shared__ float t[32][33];
    int n0 = blockIdx.x*32, k0 = blockIdx.y*32;
    int tx = threadIdx.x & 31, ty = threadIdx.x >> 5;
    #pragma unroll
    for (int i = 0; i < 32; i += 8)
        t[ty+i][tx] = in[(size_t)(k0+ty+i)*N + n0+tx];
    __syncthreads();
    #pragma unroll
    for (int i = 0; i < 32; i += 8)
        out[(size_t)(n0+ty+i)*K + k0+tx] = f2bs(t[tx][ty+i]);
}

// v_rm [8192][768] bf16 -> vT [(b*12+h)*64 + d][1024] bf16
__global__ __launch_bounds__(256) void transpose_v(const short* __restrict__ v_rm,
                                                   short* __restrict__ vT)
{
    __shared__ short t[64][65];
    int st = blockIdx.x, h = blockIdx.y, b = blockIdx.z;
    int tok = threadIdx.x >> 2, seg = (threadIdx.x & 3)*16;
    const short* src = v_rm + (size_t)(b*SEQ + st*64 + tok)*DM + h*DH + seg;
    bf16x8 a0 = *(const bf16x8*)src;
    bf16x8 a1 = *(const bf16x8*)(src + 8);
    #pragma unroll
    for (int i = 0; i < 8; i++) t[seg + i][tok]     = a0[i];
    #pragma unroll
    for (int i = 0; i < 8; i++) t[seg + 8 + i][tok] = a1[i];
    __syncthreads();
    int d = threadIdx.x >> 2; int sk = (threadIdx.x & 3)*16;
    short* dst = vT + ((size_t)(b*NH + h)*DH + d)*SEQ + st*64 + sk;
    bf16x8 w0, w1;
    #pragma unroll
    for (int i = 0; i < 8; i++) w0[i] = t[d][sk + i];
    #pragma unroll
    for (int i = 0; i < 8; i++) w1[i] = t[d][sk + 8 + i];
    *(bf16x8*)dst = w0;
    *(bf16x8*)(dst + 8) = w1;
}

// ---------------- LN fused stats+apply: fp32 [rows][768] -> bf16 xhat ----------------
__global__ __launch_bounds__(256) void ln_apply(const float* __restrict__ x,
                                                const float* __restrict__ gw,
                                                const float* __restrict__ gb,
                                                short* __restrict__ y)
{
    int wv = threadIdx.x >> 6, lane = threadIdx.x & 63;
    int row = blockIdx.x*4 + wv;
    const float* xr = x + (size_t)row*DM;
    f32x4 v[3];
    float s = 0.f, s2 = 0.f;
    #pragma unroll
    for (int i = 0; i < 3; i++){
        v[i] = *(const f32x4*)(xr + 256*i + 4*lane);
        #pragma unroll
        for (int j = 0; j < 4; j++){ s += v[i][j]; s2 += v[i][j]*v[i][j]; }
    }
    #pragma unroll
    for (int d = 1; d < 64; d <<= 1){
        s  += __shfl_xor(s,  d, 64);
        s2 += __shfl_xor(s2, d, 64);
    }
    float mean = s * (1.0f/DM);
    float r = rsqrtf(s2 * (1.0f/DM) - mean*mean + LN_EPS);
    short* yr = y + (size_t)row*DM;
    #pragma unroll
    for (int i = 0; i < 3; i++){
        int c = 256*i + 4*lane;
        f32x4 wl = *(const f32x4*)(gw + c);
        f32x4 bl = *(const f32x4*)(gb + c);
        s16x4 o;
        #pragma unroll
        for (int j = 0; j < 4; j++)
            o[j] = f2bs((v[i][j] - mean)*r*wl[j] + bl[j]);
        *(s16x4*)(yr + c) = o;
    }
}

// Swizzle (BK=32, 64B rows): data(row m, seg s) stored at seg c = s ^ ((m>>1)&3).
// Staging lane l -> row r4=l>>2, linear LDS slot l; global seg (l&3)^((r4>>1)&3).
// global_load_lds writes lane l at wave_base + l*16B == the linear slot.

// ---------------- MFMA B^T GEMM, 128x128 tile, 4-stage counted-vmcnt pipeline ---------
// LW=4 gld16/wave/tile; steady-state wait vmcnt(8) (2 tiles in flight), never 0.
// Buffer reuse: L(t+3) -> buf[(t+3)&3] == buf[(t-1)&3], last read step t-1, fenced by
// the barrier at top of step t. EPI: 1=gelu. SPLITV: cols<1536 -> Cp (stride 1536,
// Q cols <768 pre-scaled by QSCALE), cols>=1536 -> Cp2 (stride 768), both bf16.
#define G128_STEP(CUR) { \
    bf16x8 af[4], bfr[4]; \
    _Pragma("unroll") \
    for (int i = 0; i < 4; i++){ \
        int m = mrow0 + 16*i + l15; \
        af[i] = *(const bf16x8*)(&As[CUR][m*32 + ((quad ^ ((m >> 1) & 3))*8)]); \
    } \
    _Pragma("unroll") \
    for (int j = 0; j < 4; j++){ \
        int n = ncol0 + 16*j + l15; \
        bfr[j] = *(const bf16x8*)(&Bs[CUR][n*32 + ((quad ^ ((n >> 1) & 3))*8)]); \
    } \
    _Pragma("unroll") \
    for (int i = 0; i < 4; i++) \
        _Pragma("unroll") \
        for (int j = 0; j < 4; j++) \
            acc[i][j] = MFMA16(af[i], bfr[j], acc[i][j]); \
}

template<int EPI, int SPLITV>
__global__ __launch_bounds__(256) void gemm_bt(const short* __restrict__ A,
                                               const short* __restrict__ Bt,
                                               const float* __restrict__ bias,
                                               void* __restrict__ Cp,
                                               void* __restrict__ Cp2,
                                               int N, int K, int NXB)
{
    __shared__ alignas(16) short As[4][128*32];
    __shared__ alignas(16) short Bs[4][128*32];
    int tid = threadIdx.x, lane = tid & 63, w = tid >> 6;
    int l15 = lane & 15, quad = lane >> 4;
    int bx, by; xcd_map(NXB, bx, by);
    int m_base = by*128, n_base = bx*128;

    int r4 = lane >> 2;
    int sG = ((lane & 3) ^ ((r4 >> 1) & 3)) * 8;
    const short* gA0 = A  + (size_t)(m_base + 32*w      + r4)*K + sG;
    const short* gA1 = A  + (size_t)(m_base + 32*w + 16 + r4)*K + sG;
    const short* gB0 = Bt + (size_t)(n_base + 32*w      + r4)*K + sG;
    const short* gB1 = Bt + (size_t)(n_base + 32*w + 16 + r4)*K + sG;

    // prologue: tiles 0..2 in flight
    #pragma unroll
    for (int tt = 0; tt < 3; tt++){
        int off = tt << 5;
        gld16(gA0 + off, &As[tt][(2*w)*512]);
        gld16(gA1 + off, &As[tt][(2*w+1)*512]);
        gld16(gB0 + off, &Bs[tt][(2*w)*512]);
        gld16(gB1 + off, &Bs[tt][(2*w+1)*512]);
    }

    int mrow0 = (w >> 1)*64, ncol0 = (w & 1)*64;
    f32x4 acc[4][4] = {};
    int nk = K >> 5;                 // 24 for all call sites
    for (int t = 0; t + 3 < nk; t++){
        asm volatile("s_waitcnt vmcnt(8)" ::: "memory");
        __builtin_amdgcn_s_barrier();
        G128_STEP(t & 3);
        int off = (t + 3) << 5, nb = (t + 3) & 3;
        gld16(gA0 + off, &As[nb][(2*w)*512]);
        gld16(gA1 + off, &As[nb][(2*w+1)*512]);
        gld16(gB0 + off, &Bs[nb][(2*w)*512]);
        gld16(gB1 + off, &Bs[nb][(2*w+1)*512]);
    }
    asm volatile("s_waitcnt vmcnt(8)" ::: "memory");
    __builtin_amdgcn_s_barrier();
    G128_STEP((nk-3) & 3);
    asm volatile("s_waitcnt vmcnt(4)" ::: "memory");
    __builtin_amdgcn_s_barrier();
    G128_STEP((nk-2) & 3);
    asm volatile("s_waitcnt vmcnt(0)" ::: "memory");
    __builtin_amdgcn_s_barrier();
    G128_STEP((nk-1) & 3);

    #pragma unroll
    for (int i = 0; i < 4; i++){
        #pragma unroll
        for (int j = 0; j < 4; j++){
            #pragma unroll
            for (int r = 0; r < 4; r++){
                size_t row = (size_t)(m_base + mrow0 + 16*i + quad*4 + r);
                int    col = n_base + ncol0 + 16*j + l15;
                float v = acc[i][j][r] + bias[col];
                if (EPI == 1) v = gelu_f(v);
                if (SPLITV){
                    if (col < 1536){
                        float q = (col < DM) ? v*QSCALE : v;   // pre-scale Q for attn
                        ((short*)Cp)[row*1536 + col] = f2bs(q);
                    } else {
                        ((short*)Cp2)[row*768 + col - 1536] = f2bs(v);
                    }
                } else {
                    ((short*)Cp)[row*N + col] = f2bs(v);
                }
            }
        }
    }
}

// ---------------- thin MFMA GEMM: 128x64 tile, 4-stage counted-vmcnt pipeline ---------
// Epilogue: +bias +fp32 residual -> fp32 out.
#define THIN_STEP(CUR) { \
    bf16x8 af[2], bfr[4]; \
    _Pragma("unroll") \
    for (int i = 0; i < 2; i++){ \
        int m = 32*w + 16*i + l15; \
        af[i] = *(const bf16x8*)(&As[CUR][m*32 + ((quad ^ ((m >> 1) & 3))*8)]); \
    } \
    _Pragma("unroll") \
    for (int j = 0; j < 4; j++){ \
        int n = 16*j + l15; \
        bfr[j] = *(const bf16x8*)(&Bs[CUR][n*32 + ((quad ^ ((n >> 1) & 3))*8)]); \
    } \
    _Pragma("unroll") \
    for (int i = 0; i < 2; i++) \
        _Pragma("unroll") \
        for (int j = 0; j < 4; j++) \
            acc[i][j] = MFMA16(af[i], bfr[j], acc[i][j]); \
}

__global__ __launch_bounds__(256) void gemm_bt_thin(const short* __restrict__ A,
                                                    const short* __restrict__ Bt,
                                                    const float* __restrict__ bias,
                                                    const float* __restrict__ resp,
                                                    float* __restrict__ Cp,
                                                    int N, int K, int NXB)
{
    __shared__ alignas(16) short As[4][128*32];
    __shared__ alignas(16) short Bs[4][64*32];
    int tid = threadIdx.x, lane = tid & 63, w = tid >> 6;
    int l15 = lane & 15, quad = lane >> 4;
    int bx, by; xcd_map(NXB, bx, by);
    int m_base = by*128, n_base = bx*64;

    int r4 = lane >> 2;
    int sG = ((lane & 3) ^ ((r4 >> 1) & 3)) * 8;
    const short* gA0 = A  + (size_t)(m_base + 32*w      + r4)*K + sG;
    const short* gA1 = A  + (size_t)(m_base + 32*w + 16 + r4)*K + sG;
    const short* gB0 = Bt + (size_t)(n_base + 16*w      + r4)*K + sG;

    #pragma unroll
    for (int tt = 0; tt < 3; tt++){
        int off = tt << 5;
        gld16(gA0 + off, &As[tt][(2*w)*512]);
        gld16(gA1 + off, &As[tt][(2*w+1)*512]);
        gld16(gB0 + off, &Bs[tt][w*512]);
    }

    f32x4 acc[2][4] = {};
    int nk = K >> 5;                 // >= 24 for all call sites
    for (int t = 0; t + 3 < nk; t++){
        asm volatile("s_waitcnt vmcnt(6)" ::: "memory");
        __builtin_amdgcn_s_barrier();
        THIN_STEP(t & 3);
        int off = (t + 3) << 5, nb = (t + 3) & 3;
        gld16(gA0 + off, &As[nb][(2*w)*512]);
        gld16(gA1 + off, &As[nb][(2*w+1)*512]);
        gld16(gB0 + off, &Bs[nb][w*512]);
    }
    asm volatile("s_waitcnt vmcnt(6)" ::: "memory");
    __builtin_amdgcn_s_barrier();
    THIN_STEP((nk-3) & 3);
    asm volatile("s_waitcnt vmcnt(3)" ::: "memory");
    __builtin_amdgcn_s_barrier();
    THIN_STEP((nk-2) & 3);
    asm volatile("s_waitcnt vmcnt(0)" ::: "memory");
    __builtin_amdgcn_s_barrier();
    THIN_STEP((nk-1) & 3);

    #pragma unroll
    for (int i = 0; i < 2; i++){
        #pragma unroll
        for (int j = 0; j < 4; j++){
            #pragma unroll
            for (int r = 0; r < 4; r++){
                size_t row = (size_t)(m_base + 32*w + 16*i + quad*4 + r);
                int    col = n_base + 16*j + l15;
                float v = acc[i][j][r] + bias[col] + resp[row*N + col];
                Cp[row*N + col] = v;
            }
        }
    }
}

// ---------------- MFMA flash attention: gld-staged K/V dbuf, XCD-owns-heads ------------
// Q pre-scaled by 0.125*log2e -> softmax fully in exp2 domain with NO per-tile scale.
// Band max: ONE 64-lane max per wave per tile (conservative row max: P<=1 preserved,
// fp32/bf16 relative precision unaffected). Defer-max (THR=10, wave-uniform check).
// Row sums via ones-MFMA during PV cluster (l accumulates in f32x4, alpha-rescaled
// only on the rare grow path). Mask applied only on the diag tile.
__global__ __launch_bounds__(256) void flash_attn(const short* __restrict__ qk,
                                                  const short* __restrict__ vT,
                                                  short* __restrict__ z)
{
    __shared__ alignas(16) short U[4608];        // Q tile [64][64] swz / Ps [4][16][72]
    __shared__ alignas(16) short Ks[2][64*64];
    __shared__ alignas(16) short Vt[2][64*64];
    int bid = blockIdx.x;
    int xcd = bid & 7, slot = bid >> 3;
    int hb = xcd*12 + (slot >> 3);   // 0..95
    int p  = slot & 7;
    int b = hb / NH, h = hb % NH;
    int tid = threadIdx.x, lane = tid & 63, w = tid >> 6;
    int l15 = lane & 15, quad = lane >> 4;
    int r8 = lane >> 3, u8 = lane & 7;
    int useg = (u8 ^ r8) * 8;
    const float THR = 10.0f;              // defer-max threshold (log2 domain)
    const short ONE = 0x3F80;             // bf16 1.0
    const bf16x8 onesv = {ONE,ONE,ONE,ONE,ONE,ONE,ONE,ONE};

    const short* kbase = qk + DM + h*DH;
    const short* vbase = vT + (size_t)(b*NH + h)*DH*SEQ;

    for (int phase = 0; phase < 2; phase++){
        int qt = phase ? (15 - p) : p;

        __syncthreads();
        gld16(qk + (size_t)(b*SEQ + qt*64 + 16*w + r8)*1536 + h*DH + useg,     &U[(2*w)*512]);
        gld16(qk + (size_t)(b*SEQ + qt*64 + 16*w + 8 + r8)*1536 + h*DH + useg, &U[(2*w+1)*512]);
        gld16(kbase + (size_t)(b*SEQ + 16*w + r8)*1536 + useg,                 &Ks[0][(2*w)*512]);
        gld16(kbase + (size_t)(b*SEQ + 16*w + 8 + r8)*1536 + useg,             &Ks[0][(2*w+1)*512]);
        gld16(vbase + (size_t)(16*w + r8)*SEQ + useg,                          &Vt[0][(2*w)*512]);
        gld16(vbase + (size_t)(16*w + 8 + r8)*SEQ + useg,                      &Vt[0][(2*w+1)*512]);
        __syncthreads();

        bf16x8 aq[2];
        #pragma unroll
        for (int kk = 0; kk < 2; kk++)
            aq[kk] = *(const bf16x8*)(U + (16*w + l15)*64 + (((4*kk + quad) ^ (l15 & 7))*8));

        float m_state = -1e30f;
        f32x4 lsum = {};
        f32x4 o_acc[4] = {};
        int rg = qt*64 + w*16 + quad*4;

        for (int kt = 0; kt <= qt; ++kt){
            int cur = kt & 1, nxt = cur ^ 1;
            if (kt < qt){
                gld16(kbase + (size_t)(b*SEQ + (kt+1)*64 + 16*w + r8)*1536 + useg,     &Ks[nxt][(2*w)*512]);
                gld16(kbase + (size_t)(b*SEQ + (kt+1)*64 + 16*w + 8 + r8)*1536 + useg, &Ks[nxt][(2*w+1)*512]);
                gld16(vbase + (size_t)(16*w + r8)*SEQ + (kt+1)*64 + useg,              &Vt[nxt][(2*w)*512]);
                gld16(vbase + (size_t)(16*w + 8 + r8)*SEQ + (kt+1)*64 + useg,          &Vt[nxt][(2*w+1)*512]);
            }

            f32x4 s[4] = {};
            __builtin_amdgcn_s_setprio(1);
            #pragma unroll
            for (int kk = 0; kk < 2; kk++){
                int swz = ((4*kk + quad) ^ (l15 & 7)) * 8;
                #pragma unroll
                for (int j = 0; j < 4; j++){
                    bf16x8 bk = *(const bf16x8*)(&Ks[cur][(16*j + l15)*64 + swz]);
                    s[j] = MFMA16(aq[kk], bk, s[j]);
                }
            }
            __builtin_amdgcn_s_setprio(0);

            if (kt == qt){          // causal mask only on the diagonal tile
                #pragma unroll
                for (int j = 0; j < 4; j++){
                    int col_g = kt*64 + 16*j + l15;
                    #pragma unroll
                    for (int r = 0; r < 4; r++)
                        if (col_g > rg + r) s[j][r] = -1e30f;
                }
            }

            // band max: one 64-lane reduction for all 16 rows of this wave
            float mx = s[0][0];
            #pragma unroll
            for (int j = 0; j < 4; j++)
                #pragma unroll
                for (int r = 0; r < 4; r++) mx = fmaxf(mx, s[j][r]);
            #pragma unroll
            for (int d = 1; d < 64; d <<= 1) mx = fmaxf(mx, __shfl_xor(mx, d, 64));

            if (mx > m_state + THR){       // wave-uniform grow path (rare)
                float alpha = exp2f(m_state - mx);
                m_state = mx;
                #pragma unroll
                for (int j = 0; j < 4; j++)
                    #pragma unroll
                    for (int r = 0; r < 4; r++) o_acc[j][r] *= alpha;
                #pragma unroll
                for (int r = 0; r < 4; r++) lsum[r] *= alpha;
            }

            #pragma unroll
            for (int j = 0; j < 4; j++)
                #pragma unroll
                for (int r = 0; r < 4; r++)
                    U[w*1152 + (quad*4 + r)*72 + 16*j + l15] = f2bs(exp2f(s[j][r] - m_state));

            __builtin_amdgcn_s_setprio(1);
            #pragma unroll
            for (int kk = 0; kk < 2; kk++){
                bf16x8 ap = *(const bf16x8*)(U + w*1152 + l15*72 + 32*kk + quad*8);
                int swz = ((4*kk + quad) ^ (l15 & 7)) * 8;
                #pragma unroll
                for (int j = 0; j < 4; j++){
                    bf16x8 bv = *(const bf16x8*)(&Vt[cur][(16*j + l15)*64 + swz]);
                    o_acc[j] = MFMA16(ap, bv, o_acc[j]);
                }
                lsum = MFMA16(ap, onesv, lsum);   // row sums ride the matrix pipe
            }
            __builtin_amdgcn_s_setprio(0);

            __syncthreads();
        }

        #pragma unroll
        for (int r = 0; r < 4; r++){
            float inv_l = 1.0f / lsum[r];
            size_t row = (size_t)(b*SEQ + rg + r);
            #pragma unroll
            for (int j = 0; j < 4; j++)
                z[row*DM + h*DH + 16*j + l15] = f2bs(o_acc[j][r] * inv_l);
        }
    }
}

// ---------------- launch ----------------
// ws map (<= 59,909,120 B, lifetime-aliased; LN hoisted to bf16 xhat):
//   A0 [0, 3538944)          wqkvT  -> WinT (A0+A1) after O-gemm
//   A1 [3538944, 4718592)    WOT
//   A2 [4718592, 4727808)    bias_qkv fp32
//   A3 [4727808, 29893632)   qk bf16 [qkv-gemm -> flash]; head reused as xh2 after flash
//   A4 [29893632, 42476544)  v_rm -> zbuf [flash -> O]; +A5 reused as hiddenH (25MB)
//   A5 [42476544, 55059456)  xh1 [ln1 -> qkv-gemm] -> vT [transpose_v -> flash]
//   A6 [55059456, 59778048)  WoutT
// resid_mid lives in d_out (fp32). MLP runs in two 4096-row halves sharing
// hiddenH so xh2 (bf16 LN2 output) fits alongside.
extern "C" void kernel_launch(void* const* d_in, const int* in_sizes, int n_in,
                              void* d_out, int out_size, void* d_ws, size_t ws_size,
                              hipStream_t stream)
{
    const float* resid_pre = (const float*)d_in[0];
    const float* W_Q  = (const float*)d_in[1];
    const float* W_K  = (const float*)d_in[2];
    const float* W_V  = (const float*)d_in[3];
    const float* W_O  = (const float*)d_in[4];
    const float* b_Q  = (const float*)d_in[5];
    const float* b_K  = (const float*)d_in[6];
    const float* b_V  = (const float*)d_in[7];
    const float* b_O  = (const float*)d_in[8];
    const float* ln1w = (const float*)d_in[9];
    const float* ln1b = (const float*)d_in[10];
    const float* ln2w = (const float*)d_in[11];
    const float* ln2b = (const float*)d_in[12];
    const float* W_in = (const float*)d_in[13];
    const float* b_in = (const float*)d_in[14];
    const float* W_out= (const float*)d_in[15];
    const float* b_out= (const float*)d_in[16];

    char* ws = (char*)d_ws;
    short*  wqkvT    = (short*)(ws);
    short*  WOT      = (short*)(ws + 3538944);
    float*  bias_qkv = (float*)(ws + 4718592);
    short*  WinT     = (short*)(ws);             // after O-gemm (A0+A1)
    short*  qk       = (short*)(ws + 4727808);   // A3
    short*  xh2      = (short*)(ws + 4727808);   // A3 head, after flash
    short*  v_rm     = (short*)(ws + 29893632);  // A4
    short*  zbuf     = (short*)(ws + 29893632);  // A4 after transpose_v
    short*  hiddenH  = (short*)(ws + 29893632);  // A4+A5, per MLP half (25.2MB)
    short*  xh1      = (short*)(ws + 42476544);  // A5 until transpose_v
    short*  vT       = (short*)(ws + 42476544);  // A5
    short*  WoutT    = (short*)(ws + 55059456);  // A6

    // all weight prep in one launch
    prep_all<<<dim3(4609), dim3(256), 0, stream>>>(W_Q, W_K, W_V, W_O, W_out,
                                                   b_Q, b_K, b_V,
                                                   wqkvT, WOT, WoutT, bias_qkv);

    // LN1 -> bf16 xhat1, then pure-bf16 QKV projection (Q,K -> qk, V -> v_rm)
    ln_apply<<<dim3(NTOK/4), dim3(256), 0, stream>>>(resid_pre, ln1w, ln1b, xh1);
    gemm_bt<0,1><<<dim3(18*64), dim3(256), 0, stream>>>(
        xh1, wqkvT, bias_qkv, qk, v_rm, QKVN, DM, 18);

    // V transpose then flash attention (XCD-owns-heads swizzle)
    transpose_v<<<dim3(SEQ/64, NH, BATCH), dim3(256), 0, stream>>>(v_rm, vT);
    flash_attn<<<dim3(768), dim3(256), 0, stream>>>(qk, vT, zbuf);

    // O projection (thin, pipelined) + residual(resid_pre) -> d_out fp32 (resid_mid)
    gemm_bt_thin<<<dim3(12*64), dim3(256), 0, stream>>>(
        zbuf, WOT, b_O, resid_pre, (float*)d_out, DM, DM, 12);

    // W_in transpose (A0/A1 dead)
    transpose_cvt<<<dim3(96, 24), dim3(256), 0, stream>>>(W_in, WinT, DM, DMLP);

    // LN2 -> bf16 xhat2 (A3 head; qk dead)
    ln_apply<<<dim3(NTOK/4), dim3(256), 0, stream>>>((const float*)d_out, ln2w, ln2b, xh2);

    // MLP in two 4096-row halves sharing hiddenH:
    //   in: xhat2 -> hidden (gelu); out: hidden -> d_out (+bias +residual, in-place)
    for (int hh = 0; hh < 2; hh++){
        const short* a    = xh2 + (size_t)hh*4096*DM;
        float*       dres = (float*)d_out + (size_t)hh*4096*DM;
        gemm_bt<1,0><<<dim3(24*32), dim3(256), 0, stream>>>(
            a, WinT, b_in, hiddenH, nullptr, DMLP, DM, 24);
        gemm_bt_thin<<<dim3(12*32), dim3(256), 0, stream>>>(
            hiddenH, WoutT, b_out, dres, dres, DM, DMLP, 12);
    }
}

// Round 6
// 380.565 us; speedup vs baseline: 1.0571x; 1.0571x over previous
//
#include <hip/hip_runtime.h>
#include <hip/hip_bf16.h>
#include <math.h>

#define DM 768
#define NH 12
#define DH 64
#define DMLP 3072
#define BATCH 8
#define SEQ 1024
#define NTOK (BATCH*SEQ)
#define QKVN (3*DM)
#define LN_EPS 1e-5f
#define QSCALE 0.18033688011f   /* 0.125 * log2(e), folded into Q */

typedef __hip_bfloat16 bf16;
typedef __attribute__((ext_vector_type(8))) short bf16x8;
typedef __attribute__((ext_vector_type(4))) short s16x4;
typedef __attribute__((ext_vector_type(4))) float f32x4;

#define MFMA16(a,b,c) __builtin_amdgcn_mfma_f32_16x16x32_bf16((a),(b),(c),0,0,0)

__device__ __forceinline__ short f2bs(float f){
    bf16 h = __float2bfloat16(f); short s; __builtin_memcpy(&s, &h, 2); return s;
}

// gelu_new(x) = x * sigmoid(2c(x + 0.044715 x^3)), c = sqrt(2/pi). ~7 VALU ops.
__device__ __forceinline__ float gelu_f(float x){
    float y = 1.5957691216057308f*(x + 0.044715f*x*x*x);
    return x * __builtin_amdgcn_rcpf(1.0f + __expf(-y));
}

// Direct global->LDS async copy, 16B/lane. LDS dest is WAVE-UNIFORM base
// (HW writes lane i at base + i*16B); global source is per-lane (carries the
// swizzle). Tracked by vmcnt.
__device__ __forceinline__ void gld16(const void* g, void* l){
    __builtin_amdgcn_global_load_lds((__attribute__((address_space(1))) unsigned int*)g,
                                     (__attribute__((address_space(3))) unsigned int*)l,
                                     16, 0, 0);
}

// XCD-aware block decode: 1D grid, xcd = bid&7 (HW round-robin heuristic).
__device__ __forceinline__ void xcd_map(int NXB, int& bx, int& by){
    int bid = blockIdx.x;
    int xcd = bid & 7, slot = bid >> 3;
    int bands = (gridDim.x >> 3) / NXB;
    by = xcd * bands + slot / NXB;
    bx = slot % NXB;
}

// ---------------- unified weight prep: all transposes + bias concat, 1 launch ---------
__global__ __launch_bounds__(256) void prep_all(const float* __restrict__ Wq,
                                                const float* __restrict__ Wk,
                                                const float* __restrict__ Wv,
                                                const float* __restrict__ WO,
                                                const float* __restrict__ Wout,
                                                const float* __restrict__ bQ,
                                                const float* __restrict__ bK,
                                                const float* __restrict__ bV,
                                                short* __restrict__ wqkvT,
                                                short* __restrict__ WOT,
                                                short* __restrict__ WoutT,
                                                float* __restrict__ bias_qkv)
{
    int bid = blockIdx.x;
    if (bid == 4608){
        for (int idx = threadIdx.x; idx < QKVN; idx += 256){
            int which = idx / DM, hc = idx % DM;
            const float* b = (which == 0) ? bQ : ((which == 1) ? bK : bV);
            bias_qkv[idx] = b[hc];
        }
        return;
    }
    __shared__ float t[32][33];
    const float* in; short* o; int srcN, dstK, n0, k0;
    if (bid < 1728){
        int bx = bid & 1, rem = bid >> 1;
        int byy = rem % 24, bz = rem / 24;
        int which = bz / 12, h = bz % 12;
        in = (which == 0 ? Wq : which == 1 ? Wk : Wv) + (size_t)h*DM*DH;
        o  = wqkvT + ((size_t)which*DM + h*DH)*DM;
        srcN = DH; dstK = DM; n0 = bx*32; k0 = byy*32;
    } else if (bid < 2304){
        int idx = bid - 1728;
        in = WO; o = WOT; srcN = DM; dstK = DM;
        n0 = (idx % 24)*32; k0 = (idx / 24)*32;
    } else {
        int idx = bid - 2304;
        in = Wout; o = WoutT; srcN = DM; dstK = DMLP;
        n0 = (idx % 24)*32; k0 = (idx / 24)*32;
    }
    int tx = threadIdx.x & 31, ty = threadIdx.x >> 5;
    #pragma unroll
    for (int i = 0; i < 32; i += 8)
        t[ty+i][tx] = in[(size_t)(k0+ty+i)*srcN + n0+tx];
    __syncthreads();
    #pragma unroll
    for (int i = 0; i < 32; i += 8)
        o[(size_t)(n0+ty+i)*dstK + k0+tx] = f2bs(t[tx][ty+i]);
}

// ---------------- transpose + fp32->bf16 convert: out[N][K] = in[K][N] ----------------
__global__ __launch_bounds__(256) void transpose_cvt(const float* __restrict__ in,
                                                     short* __restrict__ out,
                                                     int K, int N)
{
    __shared__ float t[32][33];
    int n0 = blockIdx.x*32, k0 = blockIdx.y*32;
    int tx = threadIdx.x & 31, ty = threadIdx.x >> 5;
    #pragma unroll
    for (int i = 0; i < 32; i += 8)
        t[ty+i][tx] = in[(size_t)(k0+ty+i)*N + n0+tx];
    __syncthreads();
    #pragma unroll
    for (int i = 0; i < 32; i += 8)
        out[(size_t)(n0+ty+i)*K + k0+tx] = f2bs(t[tx][ty+i]);
}

// v_rm [8192][768] bf16 -> vT [(b*12+h)*64 + d][1024] bf16
__global__ __launch_bounds__(256) void transpose_v(const short* __restrict__ v_rm,
                                                   short* __restrict__ vT)
{
    __shared__ short t[64][65];
    int st = blockIdx.x, h = blockIdx.y, b = blockIdx.z;
    int tok = threadIdx.x >> 2, seg = (threadIdx.x & 3)*16;
    const short* src = v_rm + (size_t)(b*SEQ + st*64 + tok)*DM + h*DH + seg;
    bf16x8 a0 = *(const bf16x8*)src;
    bf16x8 a1 = *(const bf16x8*)(src + 8);
    #pragma unroll
    for (int i = 0; i < 8; i++) t[seg + i][tok]     = a0[i];
    #pragma unroll
    for (int i = 0; i < 8; i++) t[seg + 8 + i][tok] = a1[i];
    __syncthreads();
    int d = threadIdx.x >> 2; int sk = (threadIdx.x & 3)*16;
    short* dst = vT + ((size_t)(b*NH + h)*DH + d)*SEQ + st*64 + sk;
    bf16x8 w0, w1;
    #pragma unroll
    for (int i = 0; i < 8; i++) w0[i] = t[d][sk + i];
    #pragma unroll
    for (int i = 0; i < 8; i++) w1[i] = t[d][sk + 8 + i];
    *(bf16x8*)dst = w0;
    *(bf16x8*)(dst + 8) = w1;
}

// ---------------- LN fused stats+apply: fp32 [rows][768] -> bf16 xhat ----------------
__global__ __launch_bounds__(256) void ln_apply(const float* __restrict__ x,
                                                const float* __restrict__ gw,
                                                const float* __restrict__ gb,
                                                short* __restrict__ y)
{
    int wv = threadIdx.x >> 6, lane = threadIdx.x & 63;
    int row = blockIdx.x*4 + wv;
    const float* xr = x + (size_t)row*DM;
    f32x4 v[3];
    float s = 0.f, s2 = 0.f;
    #pragma unroll
    for (int i = 0; i < 3; i++){
        v[i] = *(const f32x4*)(xr + 256*i + 4*lane);
        #pragma unroll
        for (int j = 0; j < 4; j++){ s += v[i][j]; s2 += v[i][j]*v[i][j]; }
    }
    #pragma unroll
    for (int d = 1; d < 64; d <<= 1){
        s  += __shfl_xor(s,  d, 64);
        s2 += __shfl_xor(s2, d, 64);
    }
    float mean = s * (1.0f/DM);
    float r = rsqrtf(s2 * (1.0f/DM) - mean*mean + LN_EPS);
    short* yr = y + (size_t)row*DM;
    #pragma unroll
    for (int i = 0; i < 3; i++){
        int c = 256*i + 4*lane;
        f32x4 wl = *(const f32x4*)(gw + c);
        f32x4 bl = *(const f32x4*)(gb + c);
        s16x4 o;
        #pragma unroll
        for (int j = 0; j < 4; j++)
            o[j] = f2bs((v[i][j] - mean)*r*wl[j] + bl[j]);
        *(s16x4*)(yr + c) = o;
    }
}

// Swizzle (BK=32, 64B rows): data(row m, seg s) stored at seg c = s ^ ((m>>1)&3).
// Staging lane l -> row r4=l>>2, linear LDS slot l; global seg (l&3)^((r4>>1)&3).
// global_load_lds writes lane l at wave_base + l*16B == the linear slot.

// ---------------- MFMA B^T GEMM, 128x128 tile, 3-stage counted-vmcnt pipeline ---------
// LW=4 gld16/wave/tile; LDS 48 KiB (3 bufs) -> 3 blocks/CU (the 4-buf/64KiB variant
// dropped to 2 blocks/CU and regressed: r5 counters Occ 17.7/MfmaUtil 14.5).
// Steady-state wait vmcnt(4): tile t complete, tile t+1 in flight — never drain to 0.
// Buffer reuse: tile t+2 -> buf[(t+2)%3] == buf[(t-1)%3], last read step t-1, fenced
// by the barrier at top of step t. EPI: 1=gelu. SPLITV: cols<1536 -> Cp (stride 1536,
// Q cols <768 pre-scaled by QSCALE), cols>=1536 -> Cp2 (stride 768), both bf16.
#define G128_STEP(CUR) { \
    bf16x8 af[4], bfr[4]; \
    _Pragma("unroll") \
    for (int i = 0; i < 4; i++){ \
        int m = mrow0 + 16*i + l15; \
        af[i] = *(const bf16x8*)(&As[CUR][m*32 + ((quad ^ ((m >> 1) & 3))*8)]); \
    } \
    _Pragma("unroll") \
    for (int j = 0; j < 4; j++){ \
        int n = ncol0 + 16*j + l15; \
        bfr[j] = *(const bf16x8*)(&Bs[CUR][n*32 + ((quad ^ ((n >> 1) & 3))*8)]); \
    } \
    _Pragma("unroll") \
    for (int i = 0; i < 4; i++) \
        _Pragma("unroll") \
        for (int j = 0; j < 4; j++) \
            acc[i][j] = MFMA16(af[i], bfr[j], acc[i][j]); \
}

template<int EPI, int SPLITV>
__global__ __launch_bounds__(256) void gemm_bt(const short* __restrict__ A,
                                               const short* __restrict__ Bt,
                                               const float* __restrict__ bias,
                                               void* __restrict__ Cp,
                                               void* __restrict__ Cp2,
                                               int N, int K, int NXB)
{
    __shared__ alignas(16) short As[3][128*32];
    __shared__ alignas(16) short Bs[3][128*32];
    int tid = threadIdx.x, lane = tid & 63, w = tid >> 6;
    int l15 = lane & 15, quad = lane >> 4;
    int bx, by; xcd_map(NXB, bx, by);
    int m_base = by*128, n_base = bx*128;

    int r4 = lane >> 2;
    int sG = ((lane & 3) ^ ((r4 >> 1) & 3)) * 8;
    const short* gA0 = A  + (size_t)(m_base + 32*w      + r4)*K + sG;
    const short* gA1 = A  + (size_t)(m_base + 32*w + 16 + r4)*K + sG;
    const short* gB0 = Bt + (size_t)(n_base + 32*w      + r4)*K + sG;
    const short* gB1 = Bt + (size_t)(n_base + 32*w + 16 + r4)*K + sG;

    // prologue: tiles 0,1 in flight
    #pragma unroll
    for (int tt = 0; tt < 2; tt++){
        int off = tt << 5;
        gld16(gA0 + off, &As[tt][(2*w)*512]);
        gld16(gA1 + off, &As[tt][(2*w+1)*512]);
        gld16(gB0 + off, &Bs[tt][(2*w)*512]);
        gld16(gB1 + off, &Bs[tt][(2*w+1)*512]);
    }

    int mrow0 = (w >> 1)*64, ncol0 = (w & 1)*64;
    f32x4 acc[4][4] = {};
    int nk = K >> 5;                 // 24 for all call sites
    int cur = 0;
    for (int t = 0; t + 2 < nk; t++){
        asm volatile("s_waitcnt vmcnt(4)" ::: "memory");   // tile t done; t+1 in flight
        __builtin_amdgcn_s_barrier();
        G128_STEP(cur);
        int off = (t + 2) << 5;
        int nb = cur + 2; if (nb >= 3) nb -= 3;
        gld16(gA0 + off, &As[nb][(2*w)*512]);
        gld16(gA1 + off, &As[nb][(2*w+1)*512]);
        gld16(gB0 + off, &Bs[nb][(2*w)*512]);
        gld16(gB1 + off, &Bs[nb][(2*w+1)*512]);
        cur = (cur + 1 == 3) ? 0 : cur + 1;
    }
    asm volatile("s_waitcnt vmcnt(4)" ::: "memory");
    __builtin_amdgcn_s_barrier();
    G128_STEP(cur);
    cur = (cur + 1 == 3) ? 0 : cur + 1;
    asm volatile("s_waitcnt vmcnt(0)" ::: "memory");
    __builtin_amdgcn_s_barrier();
    G128_STEP(cur);

    #pragma unroll
    for (int i = 0; i < 4; i++){
        #pragma unroll
        for (int j = 0; j < 4; j++){
            #pragma unroll
            for (int r = 0; r < 4; r++){
                size_t row = (size_t)(m_base + mrow0 + 16*i + quad*4 + r);
                int    col = n_base + ncol0 + 16*j + l15;
                float v = acc[i][j][r] + bias[col];
                if (EPI == 1) v = gelu_f(v);
                if (SPLITV){
                    if (col < 1536){
                        float q = (col < DM) ? v*QSCALE : v;   // pre-scale Q for attn
                        ((short*)Cp)[row*1536 + col] = f2bs(q);
                    } else {
                        ((short*)Cp2)[row*768 + col - 1536] = f2bs(v);
                    }
                } else {
                    ((short*)Cp)[row*N + col] = f2bs(v);
                }
            }
        }
    }
}

// ---------------- thin MFMA GEMM: 128x64 tile, 4-stage counted-vmcnt pipeline ---------
// Epilogue: +bias +fp32 residual -> fp32 out.  (48 KiB LDS, validated r3.)
#define THIN_STEP(CUR) { \
    bf16x8 af[2], bfr[4]; \
    _Pragma("unroll") \
    for (int i = 0; i < 2; i++){ \
        int m = 32*w + 16*i + l15; \
        af[i] = *(const bf16x8*)(&As[CUR][m*32 + ((quad ^ ((m >> 1) & 3))*8)]); \
    } \
    _Pragma("unroll") \
    for (int j = 0; j < 4; j++){ \
        int n = 16*j + l15; \
        bfr[j] = *(const bf16x8*)(&Bs[CUR][n*32 + ((quad ^ ((n >> 1) & 3))*8)]); \
    } \
    _Pragma("unroll") \
    for (int i = 0; i < 2; i++) \
        _Pragma("unroll") \
        for (int j = 0; j < 4; j++) \
            acc[i][j] = MFMA16(af[i], bfr[j], acc[i][j]); \
}

__global__ __launch_bounds__(256) void gemm_bt_thin(const short* __restrict__ A,
                                                    const short* __restrict__ Bt,
                                                    const float* __restrict__ bias,
                                                    const float* __restrict__ resp,
                                                    float* __restrict__ Cp,
                                                    int N, int K, int NXB)
{
    __shared__ alignas(16) short As[4][128*32];
    __shared__ alignas(16) short Bs[4][64*32];
    int tid = threadIdx.x, lane = tid & 63, w = tid >> 6;
    int l15 = lane & 15, quad = lane >> 4;
    int bx, by; xcd_map(NXB, bx, by);
    int m_base = by*128, n_base = bx*64;

    int r4 = lane >> 2;
    int sG = ((lane & 3) ^ ((r4 >> 1) & 3)) * 8;
    const short* gA0 = A  + (size_t)(m_base + 32*w      + r4)*K + sG;
    const short* gA1 = A  + (size_t)(m_base + 32*w + 16 + r4)*K + sG;
    const short* gB0 = Bt + (size_t)(n_base + 16*w      + r4)*K + sG;

    #pragma unroll
    for (int tt = 0; tt < 3; tt++){
        int off = tt << 5;
        gld16(gA0 + off, &As[tt][(2*w)*512]);
        gld16(gA1 + off, &As[tt][(2*w+1)*512]);
        gld16(gB0 + off, &Bs[tt][w*512]);
    }

    f32x4 acc[2][4] = {};
    int nk = K >> 5;                 // >= 24 for all call sites
    for (int t = 0; t + 3 < nk; t++){
        asm volatile("s_waitcnt vmcnt(6)" ::: "memory");
        __builtin_amdgcn_s_barrier();
        THIN_STEP(t & 3);
        int off = (t + 3) << 5, nb = (t + 3) & 3;
        gld16(gA0 + off, &As[nb][(2*w)*512]);
        gld16(gA1 + off, &As[nb][(2*w+1)*512]);
        gld16(gB0 + off, &Bs[nb][w*512]);
    }
    asm volatile("s_waitcnt vmcnt(6)" ::: "memory");
    __builtin_amdgcn_s_barrier();
    THIN_STEP((nk-3) & 3);
    asm volatile("s_waitcnt vmcnt(3)" ::: "memory");
    __builtin_amdgcn_s_barrier();
    THIN_STEP((nk-2) & 3);
    asm volatile("s_waitcnt vmcnt(0)" ::: "memory");
    __builtin_amdgcn_s_barrier();
    THIN_STEP((nk-1) & 3);

    #pragma unroll
    for (int i = 0; i < 2; i++){
        #pragma unroll
        for (int j = 0; j < 4; j++){
            #pragma unroll
            for (int r = 0; r < 4; r++){
                size_t row = (size_t)(m_base + 32*w + 16*i + quad*4 + r);
                int    col = n_base + 16*j + l15;
                float v = acc[i][j][r] + bias[col] + resp[row*N + col];
                Cp[row*N + col] = v;
            }
        }
    }
}

// ---------------- MFMA flash attention: gld-staged K/V dbuf, XCD-owns-heads ------------
// Q pre-scaled by 0.125*log2e -> softmax fully in exp2 domain with NO per-tile scale.
// Band max: ONE 64-lane max per wave per tile (conservative row max: P<=1 preserved,
// fp32/bf16 relative precision unaffected). Defer-max (THR=10, wave-uniform check).
// Row sums via ones-MFMA during PV cluster (l accumulates in f32x4, alpha-rescaled
// only on the rare grow path). Mask applied only on the diag tile.
__global__ __launch_bounds__(256) void flash_attn(const short* __restrict__ qk,
                                                  const short* __restrict__ vT,
                                                  short* __restrict__ z)
{
    __shared__ alignas(16) short U[4608];        // Q tile [64][64] swz / Ps [4][16][72]
    __shared__ alignas(16) short Ks[2][64*64];
    __shared__ alignas(16) short Vt[2][64*64];
    int bid = blockIdx.x;
    int xcd = bid & 7, slot = bid >> 3;
    int hb = xcd*12 + (slot >> 3);   // 0..95
    int p  = slot & 7;
    int b = hb / NH, h = hb % NH;
    int tid = threadIdx.x, lane = tid & 63, w = tid >> 6;
    int l15 = lane & 15, quad = lane >> 4;
    int r8 = lane >> 3, u8 = lane & 7;
    int useg = (u8 ^ r8) * 8;
    const float THR = 10.0f;              // defer-max threshold (log2 domain)
    const short ONE = 0x3F80;             // bf16 1.0
    const bf16x8 onesv = {ONE,ONE,ONE,ONE,ONE,ONE,ONE,ONE};

    const short* kbase = qk + DM + h*DH;
    const short* vbase = vT + (size_t)(b*NH + h)*DH*SEQ;

    for (int phase = 0; phase < 2; phase++){
        int qt = phase ? (15 - p) : p;

        __syncthreads();
        gld16(qk + (size_t)(b*SEQ + qt*64 + 16*w + r8)*1536 + h*DH + useg,     &U[(2*w)*512]);
        gld16(qk + (size_t)(b*SEQ + qt*64 + 16*w + 8 + r8)*1536 + h*DH + useg, &U[(2*w+1)*512]);
        gld16(kbase + (size_t)(b*SEQ + 16*w + r8)*1536 + useg,                 &Ks[0][(2*w)*512]);
        gld16(kbase + (size_t)(b*SEQ + 16*w + 8 + r8)*1536 + useg,             &Ks[0][(2*w+1)*512]);
        gld16(vbase + (size_t)(16*w + r8)*SEQ + useg,                          &Vt[0][(2*w)*512]);
        gld16(vbase + (size_t)(16*w + 8 + r8)*SEQ + useg,                      &Vt[0][(2*w+1)*512]);
        __syncthreads();

        bf16x8 aq[2];
        #pragma unroll
        for (int kk = 0; kk < 2; kk++)
            aq[kk] = *(const bf16x8*)(U + (16*w + l15)*64 + (((4*kk + quad) ^ (l15 & 7))*8));

        float m_state = -1e30f;
        f32x4 lsum = {};
        f32x4 o_acc[4] = {};
        int rg = qt*64 + w*16 + quad*4;

        for (int kt = 0; kt <= qt; ++kt){
            int cur = kt & 1, nxt = cur ^ 1;
            if (kt < qt){
                gld16(kbase + (size_t)(b*SEQ + (kt+1)*64 + 16*w + r8)*1536 + useg,     &Ks[nxt][(2*w)*512]);
                gld16(kbase + (size_t)(b*SEQ + (kt+1)*64 + 16*w + 8 + r8)*1536 + useg, &Ks[nxt][(2*w+1)*512]);
                gld16(vbase + (size_t)(16*w + r8)*SEQ + (kt+1)*64 + useg,              &Vt[nxt][(2*w)*512]);
                gld16(vbase + (size_t)(16*w + 8 + r8)*SEQ + (kt+1)*64 + useg,          &Vt[nxt][(2*w+1)*512]);
            }

            f32x4 s[4] = {};
            __builtin_amdgcn_s_setprio(1);
            #pragma unroll
            for (int kk = 0; kk < 2; kk++){
                int swz = ((4*kk + quad) ^ (l15 & 7)) * 8;
                #pragma unroll
                for (int j = 0; j < 4; j++){
                    bf16x8 bk = *(const bf16x8*)(&Ks[cur][(16*j + l15)*64 + swz]);
                    s[j] = MFMA16(aq[kk], bk, s[j]);
                }
            }
            __builtin_amdgcn_s_setprio(0);

            if (kt == qt){          // causal mask only on the diagonal tile
                #pragma unroll
                for (int j = 0; j < 4; j++){
                    int col_g = kt*64 + 16*j + l15;
                    #pragma unroll
                    for (int r = 0; r < 4; r++)
                        if (col_g > rg + r) s[j][r] = -1e30f;
                }
            }

            // band max: one 64-lane reduction for all 16 rows of this wave
            float mx = s[0][0];
            #pragma unroll
            for (int j = 0; j < 4; j++)
                #pragma unroll
                for (int r = 0; r < 4; r++) mx = fmaxf(mx, s[j][r]);
            #pragma unroll
            for (int d = 1; d < 64; d <<= 1) mx = fmaxf(mx, __shfl_xor(mx, d, 64));

            if (mx > m_state + THR){       // wave-uniform grow path (rare)
                float alpha = exp2f(m_state - mx);
                m_state = mx;
                #pragma unroll
                for (int j = 0; j < 4; j++)
                    #pragma unroll
                    for (int r = 0; r < 4; r++) o_acc[j][r] *= alpha;
                #pragma unroll
                for (int r = 0; r < 4; r++) lsum[r] *= alpha;
            }

            #pragma unroll
            for (int j = 0; j < 4; j++)
                #pragma unroll
                for (int r = 0; r < 4; r++)
                    U[w*1152 + (quad*4 + r)*72 + 16*j + l15] = f2bs(exp2f(s[j][r] - m_state));

            __builtin_amdgcn_s_setprio(1);
            #pragma unroll
            for (int kk = 0; kk < 2; kk++){
                bf16x8 ap = *(const bf16x8*)(U + w*1152 + l15*72 + 32*kk + quad*8);
                int swz = ((4*kk + quad) ^ (l15 & 7)) * 8;
                #pragma unroll
                for (int j = 0; j < 4; j++){
                    bf16x8 bv = *(const bf16x8*)(&Vt[cur][(16*j + l15)*64 + swz]);
                    o_acc[j] = MFMA16(ap, bv, o_acc[j]);
                }
                lsum = MFMA16(ap, onesv, lsum);   // row sums ride the matrix pipe
            }
            __builtin_amdgcn_s_setprio(0);

            __syncthreads();
        }

        #pragma unroll
        for (int r = 0; r < 4; r++){
            float inv_l = 1.0f / lsum[r];
            size_t row = (size_t)(b*SEQ + rg + r);
            #pragma unroll
            for (int j = 0; j < 4; j++)
                z[row*DM + h*DH + 16*j + l15] = f2bs(o_acc[j][r] * inv_l);
        }
    }
}

// ---------------- launch ----------------
// ws map (<= 59,909,120 B, lifetime-aliased; LN hoisted to bf16 xhat):
//   A0 [0, 3538944)          wqkvT  -> WinT (A0+A1) after O-gemm
//   A1 [3538944, 4718592)    WOT
//   A2 [4718592, 4727808)    bias_qkv fp32
//   A3 [4727808, 29893632)   qk bf16 [qkv-gemm -> flash]; head reused as xh2 after flash
//   A4 [29893632, 42476544)  v_rm -> zbuf [flash -> O]; +A5 reused as hiddenH (25MB)
//   A5 [42476544, 55059456)  xh1 [ln1 -> qkv-gemm] -> vT [transpose_v -> flash]
//   A6 [55059456, 59778048)  WoutT
// resid_mid lives in d_out (fp32). MLP runs in two 4096-row halves sharing
// hiddenH so xh2 (bf16 LN2 output) fits alongside.
extern "C" void kernel_launch(void* const* d_in, const int* in_sizes, int n_in,
                              void* d_out, int out_size, void* d_ws, size_t ws_size,
                              hipStream_t stream)
{
    const float* resid_pre = (const float*)d_in[0];
    const float* W_Q  = (const float*)d_in[1];
    const float* W_K  = (const float*)d_in[2];
    const float* W_V  = (const float*)d_in[3];
    const float* W_O  = (const float*)d_in[4];
    const float* b_Q  = (const float*)d_in[5];
    const float* b_K  = (const float*)d_in[6];
    const float* b_V  = (const float*)d_in[7];
    const float* b_O  = (const float*)d_in[8];
    const float* ln1w = (const float*)d_in[9];
    const float* ln1b = (const float*)d_in[10];
    const float* ln2w = (const float*)d_in[11];
    const float* ln2b = (const float*)d_in[12];
    const float* W_in = (const float*)d_in[13];
    const float* b_in = (const float*)d_in[14];
    const float* W_out= (const float*)d_in[15];
    const float* b_out= (const float*)d_in[16];

    char* ws = (char*)d_ws;
    short*  wqkvT    = (short*)(ws);
    short*  WOT      = (short*)(ws + 3538944);
    float*  bias_qkv = (float*)(ws + 4718592);
    short*  WinT     = (short*)(ws);             // after O-gemm (A0+A1)
    short*  qk       = (short*)(ws + 4727808);   // A3
    short*  xh2      = (short*)(ws + 4727808);   // A3 head, after flash
    short*  v_rm     = (short*)(ws + 29893632);  // A4
    short*  zbuf     = (short*)(ws + 29893632);  // A4 after transpose_v
    short*  hiddenH  = (short*)(ws + 29893632);  // A4+A5, per MLP half (25.2MB)
    short*  xh1      = (short*)(ws + 42476544);  // A5 until transpose_v
    short*  vT       = (short*)(ws + 42476544);  // A5
    short*  WoutT    = (short*)(ws + 55059456);  // A6

    // all weight prep in one launch
    prep_all<<<dim3(4609), dim3(256), 0, stream>>>(W_Q, W_K, W_V, W_O, W_out,
                                                   b_Q, b_K, b_V,
                                                   wqkvT, WOT, WoutT, bias_qkv);

    // LN1 -> bf16 xhat1, then pure-bf16 QKV projection (Q,K -> qk, V -> v_rm)
    ln_apply<<<dim3(NTOK/4), dim3(256), 0, stream>>>(resid_pre, ln1w, ln1b, xh1);
    gemm_bt<0,1><<<dim3(18*64), dim3(256), 0, stream>>>(
        xh1, wqkvT, bias_qkv, qk, v_rm, QKVN, DM, 18);

    // V transpose then flash attention (XCD-owns-heads swizzle)
    transpose_v<<<dim3(SEQ/64, NH, BATCH), dim3(256), 0, stream>>>(v_rm, vT);
    flash_attn<<<dim3(768), dim3(256), 0, stream>>>(qk, vT, zbuf);

    // O projection (thin, pipelined) + residual(resid_pre) -> d_out fp32 (resid_mid)
    gemm_bt_thin<<<dim3(12*64), dim3(256), 0, stream>>>(
        zbuf, WOT, b_O, resid_pre, (float*)d_out, DM, DM, 12);

    // W_in transpose (A0/A1 dead)
    transpose_cvt<<<dim3(96, 24), dim3(256), 0, stream>>>(W_in, WinT, DM, DMLP);

    // LN2 -> bf16 xhat2 (A3 head; qk dead)
    ln_apply<<<dim3(NTOK/4), dim3(256), 0, stream>>>((const float*)d_out, ln2w, ln2b, xh2);

    // MLP in two 4096-row halves sharing hiddenH:
    //   in: xhat2 -> hidden (gelu); out: hidden -> d_out (+bias +residual, in-place)
    for (int hh = 0; hh < 2; hh++){
        const short* a    = xh2 + (size_t)hh*4096*DM;
        float*       dres = (float*)d_out + (size_t)hh*4096*DM;
        gemm_bt<1,0><<<dim3(24*32), dim3(256), 0, stream>>>(
            a, WinT, b_in, hiddenH, nullptr, DMLP, DM, 24);
        gemm_bt_thin<<<dim3(12*32), dim3(256), 0, stream>>>(
            hiddenH, WoutT, b_out, dres, dres, DM, DMLP, 12);
    }
}